// Round 4
// baseline (782.467 us; speedup 1.0000x reference)
//
#include <hip/hip_runtime.h>

// ---------------------------------------------------------------------------
// HAN link-prediction forward, fp32, CSR-based edge softmax/aggregation.
//   - _group with one metapath == identity (k*W/k*b/q* are dead params)
//   - CSR (offsets/counts/perm) built per edge list, reused by both layers
//   - per-dst-node fused softmax+aggregate: no float atomics, 1 write/row
//   - GEMM: 64xM tile, K-split (KT=64) for 16.6KB LDS -> 8 blocks/CU,
//     interleaved-k staging (2-way banks = free), scalar LDS reads (read2)
// ---------------------------------------------------------------------------

#define HEADS 4

__device__ __forceinline__ float leaky02(float a) {
    return a >= 0.f ? a : 0.2f * a;
}

// ---------------------------------------------------------------------------
// GEMM: out[n,m] = sum_k X[n,k] * W[k,m] + b[m].
// 256 threads; block tile = 64 rows x M cols; thread tile = TM rows x 4 cols.
// X staged K-major (xs[k][row], stride 65) in KT=64 chunks.
//   staging: lane handles k = 2*(tid&31)+{0,1} -> store bank (2l+r)%32, 2-way
//   compute: xs[k][r0+j] scalar reads (broadcast), W row float4 (L1/L2-hot)
// ---------------------------------------------------------------------------
template<int K, int M, int TM>
__global__ __launch_bounds__(256, 8) void gemm_bias(
    const float* __restrict__ X, const float* __restrict__ W,
    const float* __restrict__ b, float* __restrict__ out, int N) {
    constexpr int KT   = 64;
    constexpr int TPC  = M / 4;            // thread col-groups
    constexpr int RG   = 256 / TPC;        // row-groups
    constexpr int ROWS = RG * TM;          // 64 for both configs
    static_assert(ROWS == 64, "tile rows");
    static_assert(K % KT == 0, "K split");
    __shared__ float xs[KT][ROWS + 1];     // 64x65x4 = 16.6 KB

    const int row0 = blockIdx.x * ROWS;
    const int kk2  = (threadIdx.x & 31) * 2;  // k pair base within KT
    const int rr   = threadIdx.x >> 5;        // 0..7
    const int col0 = (threadIdx.x % TPC) * 4;
    const int r0   = (threadIdx.x / TPC) * TM;

    float4 acc[TM];
    #pragma unroll
    for (int j = 0; j < TM; ++j) acc[j] = make_float4(0.f, 0.f, 0.f, 0.f);

    for (int kt = 0; kt < K; kt += KT) {
        if (kt) __syncthreads();
        // stage X[row0..row0+63][kt..kt+KT) -> xs[k][r] (transposed)
        #pragma unroll
        for (int ri = 0; ri < 8; ++ri) {
            const int r  = rr + 8 * ri;
            const int gr = row0 + r;
            float2 v = (gr < N)
                ? *(const float2*)(X + (size_t)gr * K + kt + kk2)
                : make_float2(0.f, 0.f);
            xs[kk2 + 0][r] = v.x;
            xs[kk2 + 1][r] = v.y;
        }
        __syncthreads();

        #pragma unroll 4
        for (int k = 0; k < KT; ++k) {
            const float4 wv = *(const float4*)(W + (size_t)(kt + k) * M + col0);
            float xr[TM];
            #pragma unroll
            for (int j = 0; j < TM; ++j) xr[j] = xs[k][r0 + j];
            #pragma unroll
            for (int j = 0; j < TM; ++j) {
                acc[j].x += xr[j] * wv.x; acc[j].y += xr[j] * wv.y;
                acc[j].z += xr[j] * wv.z; acc[j].w += xr[j] * wv.w;
            }
        }
    }

    const float4 bv = *(const float4*)(b + col0);
    #pragma unroll
    for (int j = 0; j < TM; ++j) {
        const int gr = row0 + r0 + j;
        if (gr < N) {
            float4 o;
            o.x = acc[j].x + bv.x; o.y = acc[j].y + bv.y;
            o.z = acc[j].z + bv.z; o.w = acc[j].w + bv.w;
            *(float4*)(out + (size_t)gr * M + col0) = o;
        }
    }
}

// ---------------------------------------------------------------------------
// Per-node attention logits for both roles of this node type.
// ---------------------------------------------------------------------------
template<int F, int D>
__global__ __launch_bounds__(256) void node_alpha2(
    const float* __restrict__ hbuf,
    const float* __restrict__ svec, const float* __restrict__ dvec,
    float* __restrict__ asrc, float* __restrict__ adst, int N) {
    constexpr int LPN = F / 4;
    constexpr int LPH = D / 4;
    const int gid  = blockIdx.x * blockDim.x + threadIdx.x;
    const int node = gid / LPN;
    const int lane = gid % LPN;
    if (node >= N) return;
    const int f0 = lane * 4;
    float4 hv = *(const float4*)(hbuf + (size_t)node * F + f0);
    float4 sv = *(const float4*)(svec + f0);
    float4 dv = *(const float4*)(dvec + f0);
    float ps = hv.x * sv.x + hv.y * sv.y + hv.z * sv.z + hv.w * sv.w;
    float pd = hv.x * dv.x + hv.y * dv.y + hv.z * dv.z + hv.w * dv.w;
    #pragma unroll
    for (int off = LPH >> 1; off > 0; off >>= 1) {
        ps += __shfl_xor(ps, off);
        pd += __shfl_xor(pd, off);
    }
    if ((lane % LPH) == 0) {
        int h = lane / LPH;
        asrc[(size_t)node * HEADS + h] = ps;
        adst[(size_t)node * HEADS + h] = pd;
    }
}

// ---------------------------------------------------------------------------
// CSR build: histogram -> exclusive scan -> scatter permutation.
// ---------------------------------------------------------------------------
__global__ __launch_bounds__(256) void hist_kernel(
    const int* __restrict__ dst, int* __restrict__ counts, int E) {
    const int e = blockIdx.x * 256 + threadIdx.x;
    if (e < E) atomicAdd(counts + dst[e], 1);
}

__global__ __launch_bounds__(256) void scan_blk(
    const int* __restrict__ in, int* __restrict__ out,
    int* __restrict__ bsum, int N) {
    __shared__ int sh[256];
    const int base = blockIdx.x * 1024 + threadIdx.x * 4;
    int v[4]; int s = 0;
    #pragma unroll
    for (int j = 0; j < 4; ++j) { v[j] = (base + j < N) ? in[base + j] : 0; s += v[j]; }
    sh[threadIdx.x] = s;
    __syncthreads();
    for (int off = 1; off < 256; off <<= 1) {
        int t = (threadIdx.x >= off) ? sh[threadIdx.x - off] : 0;
        __syncthreads();
        sh[threadIdx.x] += t;
        __syncthreads();
    }
    int run = sh[threadIdx.x] - s;  // exclusive prefix of this thread
    #pragma unroll
    for (int j = 0; j < 4; ++j) {
        if (base + j < N) out[base + j] = run;
        run += v[j];
    }
    if (threadIdx.x == 255) bsum[blockIdx.x] = sh[255];
}

__global__ __launch_bounds__(256) void scan_sums(int* __restrict__ bsum, int nb) {
    __shared__ int sh[256];
    int v = (threadIdx.x < nb) ? bsum[threadIdx.x] : 0;
    sh[threadIdx.x] = v;
    __syncthreads();
    for (int off = 1; off < 256; off <<= 1) {
        int t = (threadIdx.x >= off) ? sh[threadIdx.x - off] : 0;
        __syncthreads();
        sh[threadIdx.x] += t;
        __syncthreads();
    }
    if (threadIdx.x < nb) bsum[threadIdx.x] = sh[threadIdx.x] - v;  // exclusive
}

__global__ __launch_bounds__(256) void scan_add(
    int* __restrict__ out, const int* __restrict__ bsum, int N) {
    const int base = blockIdx.x * 1024 + threadIdx.x * 4;
    const int add = bsum[blockIdx.x];
    #pragma unroll
    for (int j = 0; j < 4; ++j)
        if (base + j < N) out[base + j] += add;
}

__global__ __launch_bounds__(256) void scatter_perm(
    const int* __restrict__ src, const int* __restrict__ dst,
    const int* __restrict__ offsets, int* __restrict__ cursor,
    int* __restrict__ perm, int E) {
    const int e = blockIdx.x * 256 + threadIdx.x;
    if (e >= E) return;
    const int d = dst[e];
    const int pos = offsets[d] + atomicAdd(cursor + d, 1);
    perm[pos] = src[e];
}

// ---------------------------------------------------------------------------
// Fused per-dst softmax + aggregation over CSR segments.
// ---------------------------------------------------------------------------
template<int F, int D>
__global__ __launch_bounds__(256) void csr_attn_agg(
    const int* __restrict__ perm, const int* __restrict__ offsets,
    const int* __restrict__ counts,
    const float* __restrict__ asrc, const float* __restrict__ adst,
    const float* __restrict__ hsrc, float* __restrict__ out, int N) {
    constexpr int LPN = F / 4;
    const int gid  = blockIdx.x * 256 + threadIdx.x;
    const int node = gid / LPN;
    const int lane = gid % LPN;
    if (node >= N) return;
    const int start = offsets[node];
    const int cnt   = counts[node];
    const int f0 = lane * 4;
    const int h  = f0 / D;
    const float ad = adst[(size_t)node * HEADS + h];

    float mx = -INFINITY;
    for (int i = 0; i < cnt; ++i) {
        int s = perm[start + i];
        float a = leaky02(asrc[(size_t)s * HEADS + h] + ad);
        mx = fmaxf(mx, a);
    }

    float den = 0.f;
    float4 acc = make_float4(0.f, 0.f, 0.f, 0.f);
    for (int i = 0; i < cnt; ++i) {
        int s = perm[start + i];
        float a = leaky02(asrc[(size_t)s * HEADS + h] + ad);
        float ex = __expf(a - mx);
        den += ex;
        float4 hv = *(const float4*)(hsrc + (size_t)s * F + f0);
        acc.x += ex * hv.x; acc.y += ex * hv.y;
        acc.z += ex * hv.z; acc.w += ex * hv.w;
    }
    const float inv = 1.f / (den + 1e-16f);
    float4 o;
    o.x = fmaxf(acc.x * inv, 0.f);
    o.y = fmaxf(acc.y * inv, 0.f);
    o.z = fmaxf(acc.z * inv, 0.f);
    o.w = fmaxf(acc.w * inv, 0.f);
    *(float4*)(out + (size_t)node * F + f0) = o;
}

// ---------------------------------------------------------------------------
// Final: out[l] = dot(zp[eli0[l]], za[eli1[l]]), 64 feats (already relu'd).
// ---------------------------------------------------------------------------
__global__ __launch_bounds__(256) void edge_dot(
    const int* __restrict__ eli, const float* __restrict__ zp,
    const float* __restrict__ za, float* __restrict__ out, int L) {
    constexpr int LPE = 16;
    const int gid  = blockIdx.x * blockDim.x + threadIdx.x;
    const int e    = gid / LPE;
    const int lane = gid % LPE;
    if (e >= L) return;
    const int p = eli[e], a = eli[(size_t)L + e];
    float4 pv = *(const float4*)(zp + (size_t)p * 64 + lane * 4);
    float4 av = *(const float4*)(za + (size_t)a * 64 + lane * 4);
    float s = pv.x * av.x + pv.y * av.y + pv.z * av.z + pv.w * av.w;
    #pragma unroll
    for (int off = 8; off > 0; off >>= 1) s += __shfl_xor(s, off);
    if (lane == 0) out[e] = s;
}

// ---------------------------------------------------------------------------
static inline int cdiv(long long a, long long b) { return (int)((a + b - 1) / b); }

extern "C" void kernel_launch(void* const* d_in, const int* in_sizes, int n_in,
                              void* d_out, int out_size, void* d_ws, size_t ws_size,
                              hipStream_t stream) {
    const float* x_p  = (const float*)d_in[0];
    const float* x_a  = (const float*)d_in[1];
    const int* ei_pa  = (const int*)d_in[2];
    const int* ei_ap  = (const int*)d_in[3];
    const int* eli    = (const int*)d_in[4];
    const float* p1W = (const float*)d_in[5];
    const float* p1b = (const float*)d_in[6];
    const float* a1W = (const float*)d_in[7];
    const float* a1b = (const float*)d_in[8];
    const float* s1pa = (const float*)d_in[9];
    const float* d1pa = (const float*)d_in[10];
    const float* s1ap = (const float*)d_in[11];
    const float* d1ap = (const float*)d_in[12];
    // 13..15: k1W, k1b, q1 — dead (single-metapath group == identity)
    const float* p2W = (const float*)d_in[16];
    const float* p2b = (const float*)d_in[17];
    const float* a2W = (const float*)d_in[18];
    const float* a2b = (const float*)d_in[19];
    const float* s2pa = (const float*)d_in[20];
    const float* d2pa = (const float*)d_in[21];
    const float* s2ap = (const float*)d_in[22];
    const float* d2ap = (const float*)d_in[23];
    // 24..26: k2W, k2b, q2 — dead

    const int NP = in_sizes[0] / 128;
    const int NA = in_sizes[1] / 128;
    const int E  = in_sizes[2] / 2;
    const int L  = in_sizes[4] / 2;
    const int N  = NP;  // NP == NA

    // ---- workspace layout ----
    char* ws = (char*)d_ws;
    size_t off = 0;
    auto alloc = [&](size_t bytes) -> char* {
        char* p = ws + off;
        off += (bytes + 255) & ~(size_t)255;
        return p;
    };
    float* regA   = (float*)alloc((size_t)N * 128 * 4);  // h_p1 ; later h_p2|h_a2
    float* regB   = (float*)alloc((size_t)N * 128 * 4);  // h_a1 ; later out_p2|out_a2
    float* out_p1 = (float*)alloc((size_t)N * 128 * 4);
    float* out_a1 = (float*)alloc((size_t)N * 128 * 4);
    float* asrc_pa = (float*)alloc((size_t)N * HEADS * 4);
    float* adst_pa = (float*)alloc((size_t)N * HEADS * 4);
    float* asrc_ap = (float*)alloc((size_t)N * HEADS * 4);
    float* adst_ap = (float*)alloc((size_t)N * HEADS * 4);
    // CSR structures (layer-independent)
    int* cnt_pa = (int*)alloc((size_t)N * 4);
    int* off_pa = (int*)alloc((size_t)N * 4);
    int* perm_pa = (int*)alloc((size_t)E * 4);
    int* cnt_ap = (int*)alloc((size_t)N * 4);
    int* off_ap = (int*)alloc((size_t)N * 4);
    int* perm_ap = (int*)alloc((size_t)E * 4);
    int* cursor  = (int*)alloc((size_t)N * 4);
    int* bsum    = (int*)alloc(256 * 4);

    float* h_p1 = regA;
    float* h_a1 = regB;
    float* h_p2 = regA;
    float* h_a2 = regA + (size_t)N * 64;
    float* out_p2 = regB;
    float* out_a2 = regB + (size_t)N * 64;

    const int* src_pa = ei_pa;       // papers
    const int* dst_pa = ei_pa + E;   // authors
    const int* src_ap = ei_ap;       // authors
    const int* dst_ap = ei_ap + E;   // papers

    const int nbScan = cdiv(N, 1024);

    // ================= CSR build (both lists) =================
    hipMemsetAsync(cnt_pa, 0, (size_t)N * 4, stream);
    hist_kernel<<<cdiv(E, 256), 256, 0, stream>>>(dst_pa, cnt_pa, E);
    scan_blk<<<nbScan, 256, 0, stream>>>(cnt_pa, off_pa, bsum, N);
    scan_sums<<<1, 256, 0, stream>>>(bsum, nbScan);
    scan_add<<<nbScan, 256, 0, stream>>>(off_pa, bsum, N);
    hipMemsetAsync(cursor, 0, (size_t)N * 4, stream);
    scatter_perm<<<cdiv(E, 256), 256, 0, stream>>>(src_pa, dst_pa, off_pa, cursor, perm_pa, E);

    hipMemsetAsync(cnt_ap, 0, (size_t)N * 4, stream);
    hist_kernel<<<cdiv(E, 256), 256, 0, stream>>>(dst_ap, cnt_ap, E);
    scan_blk<<<nbScan, 256, 0, stream>>>(cnt_ap, off_ap, bsum, N);
    scan_sums<<<1, 256, 0, stream>>>(bsum, nbScan);
    scan_add<<<nbScan, 256, 0, stream>>>(off_ap, bsum, N);
    hipMemsetAsync(cursor, 0, (size_t)N * 4, stream);
    scatter_perm<<<cdiv(E, 256), 256, 0, stream>>>(src_ap, dst_ap, off_ap, cursor, perm_ap, E);

    // ================= Layer 1 =================
    gemm_bias<128, 128, 8><<<cdiv(NP, 64), 256, 0, stream>>>(x_p, p1W, p1b, h_p1, NP);
    gemm_bias<128, 128, 8><<<cdiv(NA, 64), 256, 0, stream>>>(x_a, a1W, a1b, h_a1, NA);

    node_alpha2<128, 32><<<cdiv((long long)NP * 32, 256), 256, 0, stream>>>(
        h_p1, s1pa, d1ap, asrc_pa, adst_ap, NP);
    node_alpha2<128, 32><<<cdiv((long long)NA * 32, 256), 256, 0, stream>>>(
        h_a1, s1ap, d1pa, asrc_ap, adst_pa, NA);

    // pa: papers -> authors (out_a1); ap: authors -> papers (out_p1)
    csr_attn_agg<128, 32><<<cdiv((long long)N * 32, 256), 256, 0, stream>>>(
        perm_pa, off_pa, cnt_pa, asrc_pa, adst_pa, h_p1, out_a1, N);
    csr_attn_agg<128, 32><<<cdiv((long long)N * 32, 256), 256, 0, stream>>>(
        perm_ap, off_ap, cnt_ap, asrc_ap, adst_ap, h_a1, out_p1, N);

    // ================= Layer 2 =================
    // (out_* are already relu'd by csr_attn_agg)
    gemm_bias<128, 64, 4><<<cdiv(NP, 64), 256, 0, stream>>>(out_p1, p2W, p2b, h_p2, NP);
    gemm_bias<128, 64, 4><<<cdiv(NA, 64), 256, 0, stream>>>(out_a1, a2W, a2b, h_a2, NA);

    node_alpha2<64, 16><<<cdiv((long long)NP * 16, 256), 256, 0, stream>>>(
        h_p2, s2pa, d2ap, asrc_pa, adst_ap, NP);
    node_alpha2<64, 16><<<cdiv((long long)NA * 16, 256), 256, 0, stream>>>(
        h_a2, s2ap, d2pa, asrc_ap, adst_pa, NA);

    csr_attn_agg<64, 16><<<cdiv((long long)N * 16, 256), 256, 0, stream>>>(
        perm_pa, off_pa, cnt_pa, asrc_pa, adst_pa, h_p2, out_a2, N);
    csr_attn_agg<64, 16><<<cdiv((long long)N * 16, 256), 256, 0, stream>>>(
        perm_ap, off_ap, cnt_ap, asrc_ap, adst_ap, h_a2, out_p2, N);

    // ================= Final dot =================
    edge_dot<<<cdiv((long long)L * 16, 256), 256, 0, stream>>>(
        eli, out_p2, out_a2, (float*)d_out, L);
}

// Round 5
// 624.510 us; speedup vs baseline: 1.2529x; 1.2529x over previous
//
#include <hip/hip_runtime.h>

// ---------------------------------------------------------------------------
// HAN link-prediction forward, fp32.
//   - _group with one metapath == identity (k*W/k*b/q* are dead params)
//   - concatenated 2N-segment CSR: one hist/scan/scatter serves both edge
//     lists; perm[2E] holds src ids, offsets/counts indexed by [0,2N)
//     (n<N: authors-dst via pa-list; n>=N: papers-dst via ap-list)
//   - agg is SINGLE-pass: alpha bounded (|a|<~8) so exp without max-subtract
//     is exact softmax up to fp32 rounding
//   - paper/author halves of gemm/alpha/agg fused into one grid each:
//     13 dispatches total (was 31)
//   - GEMM is the R3 (70us) version: 64xM tile, K-major LDS, TM rows/thread
// ---------------------------------------------------------------------------

#define HEADS 4

__device__ __forceinline__ float leaky02(float a) {
    return a >= 0.f ? a : 0.2f * a;
}

// ---------------------------------------------------------------------------
// Fused GEMM: half the grid does (XA,WA,bA->outA), half (XB,WB,bB->outB).
// 256 threads; block tile = 64 rows x M cols; thread tile = TM rows x 4 cols.
// X staged K-major in LDS (xs[k][row]); W rows per-k float4 (L1/L2-hot).
// ---------------------------------------------------------------------------
template<int K, int M, int TM>
__global__ __launch_bounds__(256) void gemm_bias_dual(
    const float* __restrict__ XA, const float* __restrict__ WA,
    const float* __restrict__ bA, float* __restrict__ outA,
    const float* __restrict__ XB, const float* __restrict__ WB,
    const float* __restrict__ bB, float* __restrict__ outB,
    int N, int nbHalf) {
    constexpr int TPC  = M / 4;
    constexpr int RG   = 256 / TPC;
    constexpr int ROWS = RG * TM;          // 64
    static_assert(ROWS == 64, "tile rows");
    __shared__ float xs[K][ROWS + 1];

    const bool second = blockIdx.x >= nbHalf;
    const float* __restrict__ X = second ? XB : XA;
    const float* __restrict__ W = second ? WB : WA;
    const float* __restrict__ b = second ? bB : bA;
    float* __restrict__ out     = second ? outB : outA;
    const int brow = second ? (blockIdx.x - nbHalf) : blockIdx.x;
    const int row0 = brow * ROWS;

    #pragma unroll
    for (int i = 0; i < (ROWS * K) / (256 * 4); ++i) {
        const int r  = i * 8 + (threadIdx.x >> 5);
        const int k0 = (threadIdx.x & 31) * 4;
        const int gr = row0 + r;
        float4 v = (gr < N) ? *(const float4*)(X + (size_t)gr * K + k0)
                            : make_float4(0.f, 0.f, 0.f, 0.f);
        xs[k0 + 0][r] = v.x;
        xs[k0 + 1][r] = v.y;
        xs[k0 + 2][r] = v.z;
        xs[k0 + 3][r] = v.w;
    }
    __syncthreads();

    const int col0 = (threadIdx.x % TPC) * 4;
    const int r0   = (threadIdx.x / TPC) * TM;

    float4 acc[TM];
    #pragma unroll
    for (int j = 0; j < TM; ++j) acc[j] = make_float4(0.f, 0.f, 0.f, 0.f);

    #pragma unroll 4
    for (int k = 0; k < K; ++k) {
        const float4 wv = *(const float4*)(W + (size_t)k * M + col0);
        float xr[TM];
        #pragma unroll
        for (int j4 = 0; j4 < TM / 4; ++j4) {
            float4 xv = *(const float4*)(&xs[k][r0 + j4 * 4]);
            xr[j4 * 4 + 0] = xv.x; xr[j4 * 4 + 1] = xv.y;
            xr[j4 * 4 + 2] = xv.z; xr[j4 * 4 + 3] = xv.w;
        }
        #pragma unroll
        for (int j = 0; j < TM; ++j) {
            acc[j].x += xr[j] * wv.x; acc[j].y += xr[j] * wv.y;
            acc[j].z += xr[j] * wv.z; acc[j].w += xr[j] * wv.w;
        }
    }

    const float4 bv = *(const float4*)(b + col0);
    #pragma unroll
    for (int j = 0; j < TM; ++j) {
        const int gr = row0 + r0 + j;
        if (gr < N) {
            float4 o;
            o.x = acc[j].x + bv.x; o.y = acc[j].y + bv.y;
            o.z = acc[j].z + bv.z; o.w = acc[j].w + bv.w;
            *(float4*)(out + (size_t)gr * M + col0) = o;
        }
    }
}

// ---------------------------------------------------------------------------
// Fused per-node attention logits, both node types in one grid.
//   papers  (node_g <  N): h=hP, src-vec sP -> asP[n], dst-vec dP -> adP[n]
//   authors (node_g >= N): h=hA, src-vec sA -> asA[n], dst-vec dA -> adA[n]
// ---------------------------------------------------------------------------
template<int F, int D>
__global__ __launch_bounds__(256) void node_alpha_dual(
    const float* __restrict__ hP, const float* __restrict__ sP,
    const float* __restrict__ dP, float* __restrict__ asP, float* __restrict__ adP,
    const float* __restrict__ hA, const float* __restrict__ sA,
    const float* __restrict__ dA, float* __restrict__ asA, float* __restrict__ adA,
    int N) {
    constexpr int LPN = F / 4;
    constexpr int LPH = D / 4;
    const int gid    = blockIdx.x * blockDim.x + threadIdx.x;
    const int node_g = gid / LPN;
    const int lane   = gid % LPN;
    if (node_g >= 2 * N) return;
    const bool aut = node_g >= N;
    const int node = aut ? node_g - N : node_g;
    const float* hbuf = aut ? hA : hP;
    const float* sv_p = aut ? sA : sP;
    const float* dv_p = aut ? dA : dP;
    float* as_p = aut ? asA : asP;
    float* ad_p = aut ? adA : adP;

    const int f0 = lane * 4;
    float4 hv = *(const float4*)(hbuf + (size_t)node * F + f0);
    float4 sv = *(const float4*)(sv_p + f0);
    float4 dv = *(const float4*)(dv_p + f0);
    float ps = hv.x * sv.x + hv.y * sv.y + hv.z * sv.z + hv.w * sv.w;
    float pd = hv.x * dv.x + hv.y * dv.y + hv.z * dv.z + hv.w * dv.w;
    #pragma unroll
    for (int off = LPH >> 1; off > 0; off >>= 1) {
        ps += __shfl_xor(ps, off);
        pd += __shfl_xor(pd, off);
    }
    if ((lane % LPH) == 0) {
        int h = lane / LPH;
        as_p[(size_t)node * HEADS + h] = ps;
        ad_p[(size_t)node * HEADS + h] = pd;
    }
}

// ---------------------------------------------------------------------------
// CSR build over the CONCATENATED 2N segment space.
// ---------------------------------------------------------------------------
__global__ __launch_bounds__(256) void hist_dual(
    const int* __restrict__ dst_pa, const int* __restrict__ dst_ap,
    int* __restrict__ counts, int N, int E) {
    const int eg = blockIdx.x * 256 + threadIdx.x;
    if (eg >= 2 * E) return;
    const int idx = (eg < E) ? dst_pa[eg] : (N + dst_ap[eg - E]);
    atomicAdd(counts + idx, 1);
}

__global__ __launch_bounds__(256) void scan_blk(
    const int* __restrict__ in, int* __restrict__ out,
    int* __restrict__ bsum, int N) {
    __shared__ int sh[256];
    const int base = blockIdx.x * 1024 + threadIdx.x * 4;
    int v[4]; int s = 0;
    #pragma unroll
    for (int j = 0; j < 4; ++j) { v[j] = (base + j < N) ? in[base + j] : 0; s += v[j]; }
    sh[threadIdx.x] = s;
    __syncthreads();
    for (int off = 1; off < 256; off <<= 1) {
        int t = (threadIdx.x >= off) ? sh[threadIdx.x - off] : 0;
        __syncthreads();
        sh[threadIdx.x] += t;
        __syncthreads();
    }
    int run = sh[threadIdx.x] - s;
    #pragma unroll
    for (int j = 0; j < 4; ++j) {
        if (base + j < N) out[base + j] = run;
        run += v[j];
    }
    if (threadIdx.x == 255) bsum[blockIdx.x] = sh[255];
}

__global__ __launch_bounds__(256) void scan_sums(int* __restrict__ bsum, int nb) {
    __shared__ int sh[256];
    int v = (threadIdx.x < nb) ? bsum[threadIdx.x] : 0;
    sh[threadIdx.x] = v;
    __syncthreads();
    for (int off = 1; off < 256; off <<= 1) {
        int t = (threadIdx.x >= off) ? sh[threadIdx.x - off] : 0;
        __syncthreads();
        sh[threadIdx.x] += t;
        __syncthreads();
    }
    if (threadIdx.x < nb) bsum[threadIdx.x] = sh[threadIdx.x] - v;
}

__global__ __launch_bounds__(256) void scan_add(
    int* __restrict__ out, const int* __restrict__ bsum, int N) {
    const int base = blockIdx.x * 1024 + threadIdx.x * 4;
    const int add = bsum[blockIdx.x];
    #pragma unroll
    for (int j = 0; j < 4; ++j)
        if (base + j < N) out[base + j] += add;
}

__global__ __launch_bounds__(256) void scatter_dual(
    const int* __restrict__ src_pa, const int* __restrict__ dst_pa,
    const int* __restrict__ src_ap, const int* __restrict__ dst_ap,
    const int* __restrict__ offsets, int* __restrict__ cursor,
    int* __restrict__ perm, int N, int E) {
    const int eg = blockIdx.x * 256 + threadIdx.x;
    if (eg >= 2 * E) return;
    int idx, val;
    if (eg < E) { idx = dst_pa[eg];         val = src_pa[eg]; }
    else        { idx = N + dst_ap[eg - E]; val = src_ap[eg - E]; }
    const int pos = offsets[idx] + atomicAdd(cursor + idx, 1);
    perm[pos] = val;
}

// ---------------------------------------------------------------------------
// Fused single-pass per-dst softmax + aggregation over concatenated CSR.
//   node_g <  N : author dst via pa-list: alpha tables *P, rows from hP -> outA
//   node_g >= N : paper  dst via ap-list: alpha tables *A, rows from hA -> outP
// No max-subtraction: |alpha| bounded (~8), exp is fp32-safe; softmax value
// identical to the max-shifted reference up to rounding.
// ---------------------------------------------------------------------------
template<int F, int D>
__global__ __launch_bounds__(256) void csr_attn_agg_dual(
    const int* __restrict__ perm, const int* __restrict__ offsets,
    const int* __restrict__ counts,
    const float* __restrict__ asrcP, const float* __restrict__ adstP,
    const float* __restrict__ hP, float* __restrict__ outA,
    const float* __restrict__ asrcA, const float* __restrict__ adstA,
    const float* __restrict__ hA, float* __restrict__ outP,
    int N) {
    constexpr int LPN = F / 4;
    const int gid    = blockIdx.x * 256 + threadIdx.x;
    const int node_g = gid / LPN;
    const int lane   = gid % LPN;
    if (node_g >= 2 * N) return;
    const bool second = node_g >= N;
    const int node = second ? node_g - N : node_g;
    const float* __restrict__ asrc = second ? asrcA : asrcP;
    const float* __restrict__ adst = second ? adstA : adstP;
    const float* __restrict__ hsrc = second ? hA : hP;
    float* __restrict__ out        = second ? outP : outA;

    const int start = offsets[node_g];
    const int cnt   = counts[node_g];
    const int f0 = lane * 4;
    const int h  = f0 / D;
    const float ad = adst[(size_t)node * HEADS + h];

    float den = 0.f;
    float4 acc = make_float4(0.f, 0.f, 0.f, 0.f);
    for (int i = 0; i < cnt; ++i) {
        int s = perm[start + i];
        float a = leaky02(asrc[(size_t)s * HEADS + h] + ad);
        float ex = __expf(a);
        den += ex;
        float4 hv = *(const float4*)(hsrc + (size_t)s * F + f0);
        acc.x += ex * hv.x; acc.y += ex * hv.y;
        acc.z += ex * hv.z; acc.w += ex * hv.w;
    }
    const float inv = 1.f / (den + 1e-16f);
    float4 o;
    o.x = fmaxf(acc.x * inv, 0.f);
    o.y = fmaxf(acc.y * inv, 0.f);
    o.z = fmaxf(acc.z * inv, 0.f);
    o.w = fmaxf(acc.w * inv, 0.f);
    *(float4*)(out + (size_t)node * F + f0) = o;
}

// ---------------------------------------------------------------------------
// Final: out[l] = dot(zp[eli0[l]], za[eli1[l]]), 64 feats (already relu'd).
// ---------------------------------------------------------------------------
__global__ __launch_bounds__(256) void edge_dot(
    const int* __restrict__ eli, const float* __restrict__ zp,
    const float* __restrict__ za, float* __restrict__ out, int L) {
    constexpr int LPE = 16;
    const int gid  = blockIdx.x * blockDim.x + threadIdx.x;
    const int e    = gid / LPE;
    const int lane = gid % LPE;
    if (e >= L) return;
    const int p = eli[e], a = eli[(size_t)L + e];
    float4 pv = *(const float4*)(zp + (size_t)p * 64 + lane * 4);
    float4 av = *(const float4*)(za + (size_t)a * 64 + lane * 4);
    float s = pv.x * av.x + pv.y * av.y + pv.z * av.z + pv.w * av.w;
    #pragma unroll
    for (int off = 8; off > 0; off >>= 1) s += __shfl_xor(s, off);
    if (lane == 0) out[e] = s;
}

// ---------------------------------------------------------------------------
static inline int cdiv(long long a, long long b) { return (int)((a + b - 1) / b); }

extern "C" void kernel_launch(void* const* d_in, const int* in_sizes, int n_in,
                              void* d_out, int out_size, void* d_ws, size_t ws_size,
                              hipStream_t stream) {
    const float* x_p  = (const float*)d_in[0];
    const float* x_a  = (const float*)d_in[1];
    const int* ei_pa  = (const int*)d_in[2];
    const int* ei_ap  = (const int*)d_in[3];
    const int* eli    = (const int*)d_in[4];
    const float* p1W = (const float*)d_in[5];
    const float* p1b = (const float*)d_in[6];
    const float* a1W = (const float*)d_in[7];
    const float* a1b = (const float*)d_in[8];
    const float* s1pa = (const float*)d_in[9];
    const float* d1pa = (const float*)d_in[10];
    const float* s1ap = (const float*)d_in[11];
    const float* d1ap = (const float*)d_in[12];
    // 13..15: k1W, k1b, q1 — dead (single-metapath group == identity)
    const float* p2W = (const float*)d_in[16];
    const float* p2b = (const float*)d_in[17];
    const float* a2W = (const float*)d_in[18];
    const float* a2b = (const float*)d_in[19];
    const float* s2pa = (const float*)d_in[20];
    const float* d2pa = (const float*)d_in[21];
    const float* s2ap = (const float*)d_in[22];
    const float* d2ap = (const float*)d_in[23];
    // 24..26: k2W, k2b, q2 — dead

    const int NP = in_sizes[0] / 128;
    const int NA = in_sizes[1] / 128;
    const int E  = in_sizes[2] / 2;
    const int L  = in_sizes[4] / 2;
    const int N  = NP;  // NP == NA

    // ---- workspace layout ----
    char* ws = (char*)d_ws;
    size_t off = 0;
    auto alloc = [&](size_t bytes) -> char* {
        char* p = ws + off;
        off += (bytes + 255) & ~(size_t)255;
        return p;
    };
    float* regA   = (float*)alloc((size_t)N * 128 * 4);  // h_p1 ; later h_p2|h_a2
    float* regB   = (float*)alloc((size_t)N * 128 * 4);  // h_a1 ; later out_p2|out_a2
    float* out_p1 = (float*)alloc((size_t)N * 128 * 4);
    float* out_a1 = (float*)alloc((size_t)N * 128 * 4);
    float* asrc_pa = (float*)alloc((size_t)N * HEADS * 4);
    float* adst_pa = (float*)alloc((size_t)N * HEADS * 4);
    float* asrc_ap = (float*)alloc((size_t)N * HEADS * 4);
    float* adst_ap = (float*)alloc((size_t)N * HEADS * 4);
    // CSR over concatenated 2N segments (layer-independent)
    int* cnt2    = (int*)alloc((size_t)2 * N * 4);   // counts[2N]
    int* cursor2 = (int*)alloc((size_t)2 * N * 4);   // cursor[2N] (contiguous w/ cnt2)
    int* off2    = (int*)alloc((size_t)2 * N * 4);   // offsets[2N]
    int* perm2   = (int*)alloc((size_t)2 * E * 4);   // perm[2E]
    int* bsum    = (int*)alloc(256 * 4);

    float* h_p1 = regA;
    float* h_a1 = regB;
    float* h_p2 = regA;
    float* h_a2 = regA + (size_t)N * 64;
    float* out_p2 = regB;
    float* out_a2 = regB + (size_t)N * 64;

    const int* src_pa = ei_pa;       // papers
    const int* dst_pa = ei_pa + E;   // authors
    const int* src_ap = ei_ap;       // authors
    const int* dst_ap = ei_ap + E;   // papers

    const int N2 = 2 * N;
    const int nbScan = cdiv(N2, 1024);

    // ================= CSR build (1 memset + 5 kernels) =================
    hipMemsetAsync(cnt2, 0, (size_t)4 * N * 4, stream);  // cnt2 + cursor2
    hist_dual<<<cdiv((long long)2 * E, 256), 256, 0, stream>>>(dst_pa, dst_ap, cnt2, N, E);
    scan_blk<<<nbScan, 256, 0, stream>>>(cnt2, off2, bsum, N2);
    scan_sums<<<1, 256, 0, stream>>>(bsum, nbScan);
    scan_add<<<nbScan, 256, 0, stream>>>(off2, bsum, N2);
    scatter_dual<<<cdiv((long long)2 * E, 256), 256, 0, stream>>>(
        src_pa, dst_pa, src_ap, dst_ap, off2, cursor2, perm2, N, E);

    // ================= Layer 1 (3 dispatches) =================
    {
        const int nbHalf = cdiv(N, 64);
        gemm_bias_dual<128, 128, 8><<<2 * nbHalf, 256, 0, stream>>>(
            x_p, p1W, p1b, h_p1, x_a, a1W, a1b, h_a1, N, nbHalf);
    }
    node_alpha_dual<128, 32><<<cdiv((long long)N2 * 32, 256), 256, 0, stream>>>(
        h_p1, s1pa, d1ap, asrc_pa, adst_ap,
        h_a1, s1ap, d1pa, asrc_ap, adst_pa, N);
    csr_attn_agg_dual<128, 32><<<cdiv((long long)N2 * 32, 256), 256, 0, stream>>>(
        perm2, off2, cnt2,
        asrc_pa, adst_pa, h_p1, out_a1,
        asrc_ap, adst_ap, h_a1, out_p1, N);

    // ================= Layer 2 (3 dispatches) =================
    {
        const int nbHalf = cdiv(N, 64);
        gemm_bias_dual<128, 64, 4><<<2 * nbHalf, 256, 0, stream>>>(
            out_p1, p2W, p2b, h_p2, out_a1, a2W, a2b, h_a2, N, nbHalf);
    }
    node_alpha_dual<64, 16><<<cdiv((long long)N2 * 16, 256), 256, 0, stream>>>(
        h_p2, s2pa, d2ap, asrc_pa, adst_ap,
        h_a2, s2ap, d2pa, asrc_ap, adst_pa, N);
    csr_attn_agg_dual<64, 16><<<cdiv((long long)N2 * 16, 256), 256, 0, stream>>>(
        perm2, off2, cnt2,
        asrc_pa, adst_pa, h_p2, out_a2,
        asrc_ap, adst_ap, h_a2, out_p2, N);

    // ================= Final dot =================
    edge_dot<<<cdiv((long long)L * 16, 256), 256, 0, stream>>>(
        eli, out_p2, out_a2, (float*)d_out, L);
}

// Round 6
// 476.156 us; speedup vs baseline: 1.6433x; 1.3116x over previous
//
#include <hip/hip_runtime.h>

// ---------------------------------------------------------------------------
// HAN link-prediction forward. fp16 MFMA GEMMs + fp16 intermediates,
// fp32 alpha tables / accumulation / output.
//   - _group with one metapath == identity (k*W/k*b/q* are dead params)
//   - concatenated 2N-segment CSR (one build serves both directions+layers)
//   - single-pass agg (alpha bounded -> exp without max-shift is exact)
//   - GEMM: v_mfma_f32_16x16x32_f16, 16 rows/wave, W pre-shuffled to
//     fragment order (L1-resident), LDS-transposed coalesced epilogue
// ---------------------------------------------------------------------------

#define HEADS 4

typedef _Float16 f16x8 __attribute__((ext_vector_type(8)));
typedef _Float16 f16x4 __attribute__((ext_vector_type(4)));
typedef float    f32x4 __attribute__((ext_vector_type(4)));

__device__ __forceinline__ float leaky02(float a) {
    return a >= 0.f ? a : 0.2f * a;
}

// ---------------------------------------------------------------------------
// W prep: fp32 [K=128][M] row-major -> fp16 fragment-ordered
//   Wf[((t*NT + j)*64 + lane)*8 + v] = W[t*32 + (lane>>4)*8 + v][j*16 + (lane&15)]
// ---------------------------------------------------------------------------
__device__ __forceinline__ void prep_one(const float* W, _Float16* Wf, int M, int o) {
    const int NT = M / 16;
    const int v = o & 7, lane = (o >> 3) & 63, jt = o >> 9;
    const int t = jt / NT, j = jt % NT;
    const int k = t * 32 + (lane >> 4) * 8 + v;
    const int n = j * 16 + (lane & 15);
    Wf[o] = (_Float16)W[k * M + n];
}

__global__ __launch_bounds__(256) void prep_w4(
    const float* __restrict__ W1, _Float16* __restrict__ Wf1,
    const float* __restrict__ W2, _Float16* __restrict__ Wf2,
    const float* __restrict__ W3, _Float16* __restrict__ Wf3,
    const float* __restrict__ W4, _Float16* __restrict__ Wf4) {
    int o = blockIdx.x * 256 + threadIdx.x;
    if (o < 16384)       prep_one(W1, Wf1, 128, o);
    else if (o < 32768)  prep_one(W2, Wf2, 128, o - 16384);
    else if (o < 40960)  prep_one(W3, Wf3, 64, o - 32768);
    else if (o < 49152)  prep_one(W4, Wf4, 64, o - 40960);
}

// ---------------------------------------------------------------------------
// MFMA GEMM (dual): out[n][m] = X[n][:] @ W + b, fp16 out.
// K=128. Each wave: 16 rows x M cols; 4 k-steps x (M/16) n-tiles of
// v_mfma_f32_16x16x32_f16. A from global (fp32 cvt or fp16 native),
// B from fragment-ordered Wf (L1-hot). Epilogue via LDS for coalesced b64.
// ---------------------------------------------------------------------------
template<int M, bool AHALF>
__global__ __launch_bounds__(256) void gemm_mfma_dual(
    const void* __restrict__ XA, const _Float16* __restrict__ WfA,
    const float* __restrict__ bA, _Float16* __restrict__ outA,
    const void* __restrict__ XB, const _Float16* __restrict__ WfB,
    const float* __restrict__ bB, _Float16* __restrict__ outB,
    int N, int nbHalf) {
    constexpr int NT = M / 16;
    __shared__ _Float16 stage[4][16][M + 4];   // +4 halfs: b64-aligned rows, bank-rotated

    const bool second = blockIdx.x >= nbHalf;
    const void* __restrict__ X        = second ? XB : XA;
    const _Float16* __restrict__ Wf   = second ? WfB : WfA;
    const float* __restrict__ b       = second ? bB : bA;
    _Float16* __restrict__ out        = second ? outB : outA;
    const int brow = second ? blockIdx.x - nbHalf : blockIdx.x;

    const int wave = threadIdx.x >> 6;
    const int lane = threadIdx.x & 63;
    const int row0 = (brow * 4 + wave) * 16;
    const int m    = lane & 15;
    const int quad = lane >> 4;

    f32x4 acc[NT];
    #pragma unroll
    for (int j = 0; j < NT; ++j) acc[j] = (f32x4){0.f, 0.f, 0.f, 0.f};

    int arow = row0 + m;
    if (arow >= N) arow = N - 1;

    #pragma unroll
    for (int t = 0; t < 4; ++t) {
        const int k0 = t * 32 + quad * 8;
        f16x8 a;
        if (AHALF) {
            a = *(const f16x8*)((const _Float16*)X + (size_t)arow * 128 + k0);
        } else {
            const float* xp = (const float*)X + (size_t)arow * 128 + k0;
            float4 v0 = *(const float4*)xp;
            float4 v1 = *(const float4*)(xp + 4);
            a = (f16x8){(_Float16)v0.x, (_Float16)v0.y, (_Float16)v0.z, (_Float16)v0.w,
                        (_Float16)v1.x, (_Float16)v1.y, (_Float16)v1.z, (_Float16)v1.w};
        }
        #pragma unroll
        for (int j = 0; j < NT; ++j) {
            f16x8 bf = *(const f16x8*)(Wf + ((size_t)(t * NT + j) * 64 + lane) * 8);
            acc[j] = __builtin_amdgcn_mfma_f32_16x16x32_f16(a, bf, acc[j], 0, 0, 0);
        }
    }

    // C/D: col = lane&15, row = quad*4 + reg
    #pragma unroll
    for (int j = 0; j < NT; ++j) {
        const float bias = b[j * 16 + m];
        #pragma unroll
        for (int r = 0; r < 4; ++r)
            stage[wave][quad * 4 + r][j * 16 + m] = (_Float16)(acc[j][r] + bias);
    }
    __syncthreads();

    // coalesced store: LPR lanes per row, f16x4 (8 B) each
    constexpr int LPR = M / 4;
    constexpr int RPI = 64 / LPR;
    const int lr = lane % LPR;
    const int rq = lane / LPR;
    #pragma unroll
    for (int i = 0; i < 16 / RPI; ++i) {
        const int rr = i * RPI + rq;
        const int grow = row0 + rr;
        if (grow < N) {
            f16x4 v = *(const f16x4*)(&stage[wave][rr][lr * 4]);
            *(f16x4*)(out + (size_t)grow * M + lr * 4) = v;
        }
    }
}

// ---------------------------------------------------------------------------
// Fused per-node attention logits (fp16 h), both node types in one grid.
// ---------------------------------------------------------------------------
template<int F, int D>
__global__ __launch_bounds__(256) void node_alpha_dual(
    const _Float16* __restrict__ hP, const float* __restrict__ sP,
    const float* __restrict__ dP, float* __restrict__ asP, float* __restrict__ adP,
    const _Float16* __restrict__ hA, const float* __restrict__ sA,
    const float* __restrict__ dA, float* __restrict__ asA, float* __restrict__ adA,
    int N) {
    constexpr int LPN = F / 4;
    constexpr int LPH = D / 4;
    const int gid    = blockIdx.x * blockDim.x + threadIdx.x;
    const int node_g = gid / LPN;
    const int lane   = gid % LPN;
    if (node_g >= 2 * N) return;
    const bool aut = node_g >= N;
    const int node = aut ? node_g - N : node_g;
    const _Float16* hbuf = aut ? hA : hP;
    const float* sv_p = aut ? sA : sP;
    const float* dv_p = aut ? dA : dP;
    float* as_p = aut ? asA : asP;
    float* ad_p = aut ? adA : adP;

    const int f0 = lane * 4;
    f16x4 h4 = *(const f16x4*)(hbuf + (size_t)node * F + f0);
    float4 sv = *(const float4*)(sv_p + f0);
    float4 dv = *(const float4*)(dv_p + f0);
    const float h0 = (float)h4[0], h1 = (float)h4[1], h2 = (float)h4[2], h3 = (float)h4[3];
    float ps = h0 * sv.x + h1 * sv.y + h2 * sv.z + h3 * sv.w;
    float pd = h0 * dv.x + h1 * dv.y + h2 * dv.z + h3 * dv.w;
    #pragma unroll
    for (int off = LPH >> 1; off > 0; off >>= 1) {
        ps += __shfl_xor(ps, off);
        pd += __shfl_xor(pd, off);
    }
    if ((lane % LPH) == 0) {
        int h = lane / LPH;
        as_p[(size_t)node * HEADS + h] = ps;
        ad_p[(size_t)node * HEADS + h] = pd;
    }
}

// ---------------------------------------------------------------------------
// CSR build over the CONCATENATED 2N segment space.
// ---------------------------------------------------------------------------
__global__ __launch_bounds__(256) void hist_dual(
    const int* __restrict__ dst_pa, const int* __restrict__ dst_ap,
    int* __restrict__ counts, int N, int E) {
    const int eg = blockIdx.x * 256 + threadIdx.x;
    if (eg >= 2 * E) return;
    const int idx = (eg < E) ? dst_pa[eg] : (N + dst_ap[eg - E]);
    atomicAdd(counts + idx, 1);
}

__global__ __launch_bounds__(256) void scan_blk(
    const int* __restrict__ in, int* __restrict__ out,
    int* __restrict__ bsum, int N) {
    __shared__ int sh[256];
    const int base = blockIdx.x * 1024 + threadIdx.x * 4;
    int v[4]; int s = 0;
    #pragma unroll
    for (int j = 0; j < 4; ++j) { v[j] = (base + j < N) ? in[base + j] : 0; s += v[j]; }
    sh[threadIdx.x] = s;
    __syncthreads();
    for (int off = 1; off < 256; off <<= 1) {
        int t = (threadIdx.x >= off) ? sh[threadIdx.x - off] : 0;
        __syncthreads();
        sh[threadIdx.x] += t;
        __syncthreads();
    }
    int run = sh[threadIdx.x] - s;
    #pragma unroll
    for (int j = 0; j < 4; ++j) {
        if (base + j < N) out[base + j] = run;
        run += v[j];
    }
    if (threadIdx.x == 255) bsum[blockIdx.x] = sh[255];
}

__global__ __launch_bounds__(256) void scan_sums(int* __restrict__ bsum, int nb) {
    __shared__ int sh[256];
    int v = (threadIdx.x < nb) ? bsum[threadIdx.x] : 0;
    sh[threadIdx.x] = v;
    __syncthreads();
    for (int off = 1; off < 256; off <<= 1) {
        int t = (threadIdx.x >= off) ? sh[threadIdx.x - off] : 0;
        __syncthreads();
        sh[threadIdx.x] += t;
        __syncthreads();
    }
    if (threadIdx.x < nb) bsum[threadIdx.x] = sh[threadIdx.x] - v;
}

__global__ __launch_bounds__(256) void scan_add(
    int* __restrict__ out, const int* __restrict__ bsum, int N) {
    const int base = blockIdx.x * 1024 + threadIdx.x * 4;
    const int add = bsum[blockIdx.x];
    #pragma unroll
    for (int j = 0; j < 4; ++j)
        if (base + j < N) out[base + j] += add;
}

__global__ __launch_bounds__(256) void scatter_dual(
    const int* __restrict__ src_pa, const int* __restrict__ dst_pa,
    const int* __restrict__ src_ap, const int* __restrict__ dst_ap,
    const int* __restrict__ offsets, int* __restrict__ cursor,
    int* __restrict__ perm, int N, int E) {
    const int eg = blockIdx.x * 256 + threadIdx.x;
    if (eg >= 2 * E) return;
    int idx, val;
    if (eg < E) { idx = dst_pa[eg];         val = src_pa[eg]; }
    else        { idx = N + dst_ap[eg - E]; val = src_ap[eg - E]; }
    const int pos = offsets[idx] + atomicAdd(cursor + idx, 1);
    perm[pos] = val;
}

// ---------------------------------------------------------------------------
// Fused single-pass per-dst softmax + aggregation (fp16 h in, fp16 out).
// ---------------------------------------------------------------------------
template<int F, int D>
__global__ __launch_bounds__(256) void csr_attn_agg_dual(
    const int* __restrict__ perm, const int* __restrict__ offsets,
    const int* __restrict__ counts,
    const float* __restrict__ asrcP, const float* __restrict__ adstP,
    const _Float16* __restrict__ hP, _Float16* __restrict__ outA,
    const float* __restrict__ asrcA, const float* __restrict__ adstA,
    const _Float16* __restrict__ hA, _Float16* __restrict__ outP,
    int N) {
    constexpr int LPN = F / 4;
    const int gid    = blockIdx.x * 256 + threadIdx.x;
    const int node_g = gid / LPN;
    const int lane   = gid % LPN;
    if (node_g >= 2 * N) return;
    const bool second = node_g >= N;
    const int node = second ? node_g - N : node_g;
    const float* __restrict__ asrc    = second ? asrcA : asrcP;
    const float* __restrict__ adst    = second ? adstA : adstP;
    const _Float16* __restrict__ hsrc = second ? hA : hP;
    _Float16* __restrict__ out        = second ? outP : outA;

    const int start = offsets[node_g];
    const int cnt   = counts[node_g];
    const int f0 = lane * 4;
    const int h  = f0 / D;
    const float ad = adst[(size_t)node * HEADS + h];

    float den = 0.f;
    float4 acc = make_float4(0.f, 0.f, 0.f, 0.f);
    for (int i = 0; i < cnt; ++i) {
        int s = perm[start + i];
        float a = leaky02(asrc[(size_t)s * HEADS + h] + ad);
        float ex = __expf(a);
        den += ex;
        f16x4 hv = *(const f16x4*)(hsrc + (size_t)s * F + f0);
        acc.x += ex * (float)hv[0]; acc.y += ex * (float)hv[1];
        acc.z += ex * (float)hv[2]; acc.w += ex * (float)hv[3];
    }
    const float inv = 1.f / (den + 1e-16f);
    f16x4 o;
    o[0] = (_Float16)fmaxf(acc.x * inv, 0.f);
    o[1] = (_Float16)fmaxf(acc.y * inv, 0.f);
    o[2] = (_Float16)fmaxf(acc.z * inv, 0.f);
    o[3] = (_Float16)fmaxf(acc.w * inv, 0.f);
    *(f16x4*)(out + (size_t)node * F + f0) = o;
}

// ---------------------------------------------------------------------------
// Final: out[l] = dot(zp[eli0[l]], za[eli1[l]]), 64 fp16 feats -> fp32.
// ---------------------------------------------------------------------------
__global__ __launch_bounds__(256) void edge_dot(
    const int* __restrict__ eli, const _Float16* __restrict__ zp,
    const _Float16* __restrict__ za, float* __restrict__ out, int L) {
    constexpr int LPE = 16;
    const int gid  = blockIdx.x * blockDim.x + threadIdx.x;
    const int e    = gid / LPE;
    const int lane = gid % LPE;
    if (e >= L) return;
    const int p = eli[e], a = eli[(size_t)L + e];
    f16x4 pv = *(const f16x4*)(zp + (size_t)p * 64 + lane * 4);
    f16x4 av = *(const f16x4*)(za + (size_t)a * 64 + lane * 4);
    float s = (float)pv[0] * (float)av[0] + (float)pv[1] * (float)av[1]
            + (float)pv[2] * (float)av[2] + (float)pv[3] * (float)av[3];
    #pragma unroll
    for (int off = 8; off > 0; off >>= 1) s += __shfl_xor(s, off);
    if (lane == 0) out[e] = s;
}

// ---------------------------------------------------------------------------
static inline int cdiv(long long a, long long b) { return (int)((a + b - 1) / b); }

extern "C" void kernel_launch(void* const* d_in, const int* in_sizes, int n_in,
                              void* d_out, int out_size, void* d_ws, size_t ws_size,
                              hipStream_t stream) {
    const float* x_p  = (const float*)d_in[0];
    const float* x_a  = (const float*)d_in[1];
    const int* ei_pa  = (const int*)d_in[2];
    const int* ei_ap  = (const int*)d_in[3];
    const int* eli    = (const int*)d_in[4];
    const float* p1W = (const float*)d_in[5];
    const float* p1b = (const float*)d_in[6];
    const float* a1W = (const float*)d_in[7];
    const float* a1b = (const float*)d_in[8];
    const float* s1pa = (const float*)d_in[9];
    const float* d1pa = (const float*)d_in[10];
    const float* s1ap = (const float*)d_in[11];
    const float* d1ap = (const float*)d_in[12];
    // 13..15: k1W, k1b, q1 — dead (single-metapath group == identity)
    const float* p2W = (const float*)d_in[16];
    const float* p2b = (const float*)d_in[17];
    const float* a2W = (const float*)d_in[18];
    const float* a2b = (const float*)d_in[19];
    const float* s2pa = (const float*)d_in[20];
    const float* d2pa = (const float*)d_in[21];
    const float* s2ap = (const float*)d_in[22];
    const float* d2ap = (const float*)d_in[23];
    // 24..26: k2W, k2b, q2 — dead

    const int NP = in_sizes[0] / 128;
    const int E  = in_sizes[2] / 2;
    const int L  = in_sizes[4] / 2;
    const int N  = NP;  // NP == NA

    // ---- workspace layout ----
    char* ws = (char*)d_ws;
    size_t off = 0;
    auto alloc = [&](size_t bytes) -> char* {
        char* p = ws + off;
        off += (bytes + 255) & ~(size_t)255;
        return p;
    };
    _Float16* h_p1   = (_Float16*)alloc((size_t)N * 128 * 2);
    _Float16* h_a1   = (_Float16*)alloc((size_t)N * 128 * 2);
    _Float16* out_p1 = (_Float16*)alloc((size_t)N * 128 * 2);
    _Float16* out_a1 = (_Float16*)alloc((size_t)N * 128 * 2);
    _Float16* h_p2   = (_Float16*)alloc((size_t)N * 64 * 2);
    _Float16* h_a2   = (_Float16*)alloc((size_t)N * 64 * 2);
    _Float16* out_p2 = (_Float16*)alloc((size_t)N * 64 * 2);
    _Float16* out_a2 = (_Float16*)alloc((size_t)N * 64 * 2);
    float* asrc_pa = (float*)alloc((size_t)N * HEADS * 4);
    float* adst_pa = (float*)alloc((size_t)N * HEADS * 4);
    float* asrc_ap = (float*)alloc((size_t)N * HEADS * 4);
    float* adst_ap = (float*)alloc((size_t)N * HEADS * 4);
    _Float16* Wf1p = (_Float16*)alloc(16384 * 2);
    _Float16* Wf1a = (_Float16*)alloc(16384 * 2);
    _Float16* Wf2p = (_Float16*)alloc(8192 * 2);
    _Float16* Wf2a = (_Float16*)alloc(8192 * 2);
    int* cnt2    = (int*)alloc((size_t)2 * N * 4);
    int* cursor2 = (int*)alloc((size_t)2 * N * 4);   // contiguous with cnt2
    int* off2    = (int*)alloc((size_t)2 * N * 4);
    int* perm2   = (int*)alloc((size_t)2 * E * 4);
    int* bsum    = (int*)alloc(256 * 4);

    const int* src_pa = ei_pa;       // papers
    const int* dst_pa = ei_pa + E;   // authors
    const int* src_ap = ei_ap;       // authors
    const int* dst_ap = ei_ap + E;   // papers

    const int N2 = 2 * N;
    const int nbScan = cdiv(N2, 1024);

    // ================= prep + CSR build =================
    prep_w4<<<cdiv(49152, 256), 256, 0, stream>>>(p1W, Wf1p, a1W, Wf1a, p2W, Wf2p, a2W, Wf2a);
    hipMemsetAsync(cnt2, 0, (size_t)4 * N * 4, stream);  // cnt2 + cursor2
    hist_dual<<<cdiv((long long)2 * E, 256), 256, 0, stream>>>(dst_pa, dst_ap, cnt2, N, E);
    scan_blk<<<nbScan, 256, 0, stream>>>(cnt2, off2, bsum, N2);
    scan_sums<<<1, 256, 0, stream>>>(bsum, nbScan);
    scan_add<<<nbScan, 256, 0, stream>>>(off2, bsum, N2);
    scatter_dual<<<cdiv((long long)2 * E, 256), 256, 0, stream>>>(
        src_pa, dst_pa, src_ap, dst_ap, off2, cursor2, perm2, N, E);

    const int nbHalf = cdiv(N, 64);

    // ================= Layer 1 =================
    gemm_mfma_dual<128, false><<<2 * nbHalf, 256, 0, stream>>>(
        x_p, Wf1p, p1b, h_p1, x_a, Wf1a, a1b, h_a1, N, nbHalf);
    node_alpha_dual<128, 32><<<cdiv((long long)N2 * 32, 256), 256, 0, stream>>>(
        h_p1, s1pa, d1ap, asrc_pa, adst_ap,
        h_a1, s1ap, d1pa, asrc_ap, adst_pa, N);
    csr_attn_agg_dual<128, 32><<<cdiv((long long)N2 * 32, 256), 256, 0, stream>>>(
        perm2, off2, cnt2,
        asrc_pa, adst_pa, h_p1, out_a1,
        asrc_ap, adst_ap, h_a1, out_p1, N);

    // ================= Layer 2 =================
    gemm_mfma_dual<64, true><<<2 * nbHalf, 256, 0, stream>>>(
        out_p1, Wf2p, p2b, h_p2, out_a1, Wf2a, a2b, h_a2, N, nbHalf);
    node_alpha_dual<64, 16><<<cdiv((long long)N2 * 16, 256), 256, 0, stream>>>(
        h_p2, s2pa, d2ap, asrc_pa, adst_ap,
        h_a2, s2ap, d2pa, asrc_ap, adst_pa, N);
    csr_attn_agg_dual<64, 16><<<cdiv((long long)N2 * 16, 256), 256, 0, stream>>>(
        perm2, off2, cnt2,
        asrc_pa, adst_pa, h_p2, out_a2,
        asrc_ap, adst_ap, h_a2, out_p2, N);

    // ================= Final dot =================
    edge_dot<<<cdiv((long long)L * 16, 256), 256, 0, stream>>>(
        eli, out_p2, out_a2, (float*)d_out, L);
}

// Round 7
// 465.218 us; speedup vs baseline: 1.6819x; 1.0235x over previous
//
#include <hip/hip_runtime.h>

// ---------------------------------------------------------------------------
// HAN link-prediction forward. fp16 MFMA GEMMs + fp16 intermediates,
// fp32 alpha tables / accumulation / output.
//   - _group with one metapath == identity (k*W/k*b/q* are dead params)
//   - concatenated 2N-segment CSR (one build serves both directions+layers)
//   - degree-bucketed node order: nodes sharing a wave have equal in-degree
//   - single-pass agg (alpha bounded -> exp without max-shift is exact),
//     4x-unrolled inner loop for memory-level parallelism
//   - GEMM: v_mfma_f32_16x16x32_f16, W pre-shuffled to fragment order,
//     alpha (src/dst logits) fused into the epilogue from the LDS tile
// ---------------------------------------------------------------------------

#define HEADS 4

typedef _Float16 f16x8 __attribute__((ext_vector_type(8)));
typedef _Float16 f16x4 __attribute__((ext_vector_type(4)));
typedef float    f32x4 __attribute__((ext_vector_type(4)));

__device__ __forceinline__ float leaky02(float a) {
    return a >= 0.f ? a : 0.2f * a;
}

// ---------------------------------------------------------------------------
// W prep: fp32 [K=128][M] row-major -> fp16 fragment-ordered
// ---------------------------------------------------------------------------
__device__ __forceinline__ void prep_one(const float* W, _Float16* Wf, int M, int o) {
    const int NT = M / 16;
    const int v = o & 7, lane = (o >> 3) & 63, jt = o >> 9;
    const int t = jt / NT, j = jt % NT;
    const int k = t * 32 + (lane >> 4) * 8 + v;
    const int n = j * 16 + (lane & 15);
    Wf[o] = (_Float16)W[k * M + n];
}

__global__ __launch_bounds__(256) void prep_w4(
    const float* __restrict__ W1, _Float16* __restrict__ Wf1,
    const float* __restrict__ W2, _Float16* __restrict__ Wf2,
    const float* __restrict__ W3, _Float16* __restrict__ Wf3,
    const float* __restrict__ W4, _Float16* __restrict__ Wf4) {
    int o = blockIdx.x * 256 + threadIdx.x;
    if (o < 16384)       prep_one(W1, Wf1, 128, o);
    else if (o < 32768)  prep_one(W2, Wf2, 128, o - 16384);
    else if (o < 40960)  prep_one(W3, Wf3, 64, o - 32768);
    else if (o < 49152)  prep_one(W4, Wf4, 64, o - 40960);
}

// ---------------------------------------------------------------------------
// MFMA GEMM (dual) with fused alpha epilogue.
// Each wave: 16 rows x M cols. After MFMA, the fp16 tile sits in wave-private
// LDS; lane (r=lane>>2, h=lane&3) computes <h[r,head h],svec[h]> and
// <.,dvec[h]> and writes asb/adb (coalesced: consecutive addresses per lane).
// ---------------------------------------------------------------------------
template<int M, bool AHALF>
__global__ __launch_bounds__(256) void gemm_mfma_dual(
    const void* __restrict__ XA, const _Float16* __restrict__ WfA,
    const float* __restrict__ bA, _Float16* __restrict__ outA,
    const float* __restrict__ svA, const float* __restrict__ dvA,
    float* __restrict__ asA, float* __restrict__ adA,
    const void* __restrict__ XB, const _Float16* __restrict__ WfB,
    const float* __restrict__ bB, _Float16* __restrict__ outB,
    const float* __restrict__ svB, const float* __restrict__ dvB,
    float* __restrict__ asB, float* __restrict__ adB,
    int N, int nbHalf) {
    constexpr int NT = M / 16;
    constexpr int D  = M / HEADS;
    __shared__ _Float16 stage[4][16][M + 4];

    const bool second = blockIdx.x >= nbHalf;
    const void* __restrict__ X      = second ? XB : XA;
    const _Float16* __restrict__ Wf = second ? WfB : WfA;
    const float* __restrict__ b     = second ? bB : bA;
    _Float16* __restrict__ out      = second ? outB : outA;
    const float* __restrict__ sv    = second ? svB : svA;
    const float* __restrict__ dv    = second ? dvB : dvA;
    float* __restrict__ asb         = second ? asB : asA;
    float* __restrict__ adb         = second ? adB : adA;
    const int brow = second ? blockIdx.x - nbHalf : blockIdx.x;

    const int wave = threadIdx.x >> 6;
    const int lane = threadIdx.x & 63;
    const int row0 = (brow * 4 + wave) * 16;
    const int m    = lane & 15;
    const int quad = lane >> 4;

    f32x4 acc[NT];
    #pragma unroll
    for (int j = 0; j < NT; ++j) acc[j] = (f32x4){0.f, 0.f, 0.f, 0.f};

    int arow = row0 + m;
    if (arow >= N) arow = N - 1;

    #pragma unroll
    for (int t = 0; t < 4; ++t) {
        const int k0 = t * 32 + quad * 8;
        f16x8 a;
        if (AHALF) {
            a = *(const f16x8*)((const _Float16*)X + (size_t)arow * 128 + k0);
        } else {
            const float* xp = (const float*)X + (size_t)arow * 128 + k0;
            float4 v0 = *(const float4*)xp;
            float4 v1 = *(const float4*)(xp + 4);
            a = (f16x8){(_Float16)v0.x, (_Float16)v0.y, (_Float16)v0.z, (_Float16)v0.w,
                        (_Float16)v1.x, (_Float16)v1.y, (_Float16)v1.z, (_Float16)v1.w};
        }
        #pragma unroll
        for (int j = 0; j < NT; ++j) {
            f16x8 bf = *(const f16x8*)(Wf + ((size_t)(t * NT + j) * 64 + lane) * 8);
            acc[j] = __builtin_amdgcn_mfma_f32_16x16x32_f16(a, bf, acc[j], 0, 0, 0);
        }
    }

    // C/D: col = lane&15, row = quad*4 + reg  (stage is wave-private; no barrier)
    #pragma unroll
    for (int j = 0; j < NT; ++j) {
        const float bias = b[j * 16 + m];
        #pragma unroll
        for (int r = 0; r < 4; ++r)
            stage[wave][quad * 4 + r][j * 16 + m] = (_Float16)(acc[j][r] + bias);
    }

    // fused alpha: lane -> (row r, head hh)
    {
        const int r  = lane >> 2;
        const int hh = lane & 3;
        float ps = 0.f, pd = 0.f;
        #pragma unroll
        for (int j = 0; j < D / 4; ++j) {
            f16x4 v4 = *(const f16x4*)(&stage[wave][r][hh * D + 4 * j]);
            float4 s4 = *(const float4*)(sv + hh * D + 4 * j);
            float4 d4 = *(const float4*)(dv + hh * D + 4 * j);
            const float v0 = (float)v4[0], v1 = (float)v4[1],
                        v2 = (float)v4[2], v3 = (float)v4[3];
            ps += v0 * s4.x + v1 * s4.y + v2 * s4.z + v3 * s4.w;
            pd += v0 * d4.x + v1 * d4.y + v2 * d4.z + v3 * d4.w;
        }
        const int grow = row0 + r;
        if (grow < N) {
            asb[(size_t)grow * HEADS + hh] = ps;
            adb[(size_t)grow * HEADS + hh] = pd;
        }
    }

    // coalesced fp16 store
    constexpr int LPR = M / 4;
    constexpr int RPI = 64 / LPR;
    const int lr = lane % LPR;
    const int rq = lane / LPR;
    #pragma unroll
    for (int i = 0; i < 16 / RPI; ++i) {
        const int rr = i * RPI + rq;
        const int grow = row0 + rr;
        if (grow < N) {
            f16x4 v = *(const f16x4*)(&stage[wave][rr][lr * 4]);
            *(f16x4*)(out + (size_t)grow * M + lr * 4) = v;
        }
    }
}

// ---------------------------------------------------------------------------
// CSR build over the CONCATENATED 2N segment space.
// ---------------------------------------------------------------------------
__global__ __launch_bounds__(256) void hist_dual(
    const int* __restrict__ dst_pa, const int* __restrict__ dst_ap,
    int* __restrict__ counts, int N, int E) {
    const int eg = blockIdx.x * 256 + threadIdx.x;
    if (eg >= 2 * E) return;
    const int idx = (eg < E) ? dst_pa[eg] : (N + dst_ap[eg - E]);
    atomicAdd(counts + idx, 1);
}

__global__ __launch_bounds__(256) void scan_blk(
    const int* __restrict__ in, int* __restrict__ out,
    int* __restrict__ bsum, int N) {
    __shared__ int sh[256];
    const int base = blockIdx.x * 1024 + threadIdx.x * 4;
    int v[4]; int s = 0;
    #pragma unroll
    for (int j = 0; j < 4; ++j) { v[j] = (base + j < N) ? in[base + j] : 0; s += v[j]; }
    sh[threadIdx.x] = s;
    __syncthreads();
    for (int off = 1; off < 256; off <<= 1) {
        int t = (threadIdx.x >= off) ? sh[threadIdx.x - off] : 0;
        __syncthreads();
        sh[threadIdx.x] += t;
        __syncthreads();
    }
    int run = sh[threadIdx.x] - s;
    #pragma unroll
    for (int j = 0; j < 4; ++j) {
        if (base + j < N) out[base + j] = run;
        run += v[j];
    }
    if (threadIdx.x == 255) bsum[blockIdx.x] = sh[255];
}

__global__ __launch_bounds__(256) void scan_sums(int* __restrict__ bsum, int nb) {
    __shared__ int sh[256];
    int v = (threadIdx.x < nb) ? bsum[threadIdx.x] : 0;
    sh[threadIdx.x] = v;
    __syncthreads();
    for (int off = 1; off < 256; off <<= 1) {
        int t = (threadIdx.x >= off) ? sh[threadIdx.x - off] : 0;
        __syncthreads();
        sh[threadIdx.x] += t;
        __syncthreads();
    }
    if (threadIdx.x < nb) bsum[threadIdx.x] = sh[threadIdx.x] - v;
}

__global__ __launch_bounds__(256) void scan_add(
    int* __restrict__ out, const int* __restrict__ bsum, int N) {
    const int base = blockIdx.x * 1024 + threadIdx.x * 4;
    const int add = bsum[blockIdx.x];
    #pragma unroll
    for (int j = 0; j < 4; ++j)
        if (base + j < N) out[base + j] += add;
}

__global__ __launch_bounds__(256) void scatter_dual(
    const int* __restrict__ src_pa, const int* __restrict__ dst_pa,
    const int* __restrict__ src_ap, const int* __restrict__ dst_ap,
    const int* __restrict__ offsets, int* __restrict__ cursor,
    int* __restrict__ perm, int N, int E) {
    const int eg = blockIdx.x * 256 + threadIdx.x;
    if (eg >= 2 * E) return;
    int idx, val;
    if (eg < E) { idx = dst_pa[eg];         val = src_pa[eg]; }
    else        { idx = N + dst_ap[eg - E]; val = src_ap[eg - E]; }
    const int pos = offsets[idx] + atomicAdd(cursor + idx, 1);
    perm[pos] = val;
}

// ---------------------------------------------------------------------------
// Degree bucket sort of the 2N segments (64 buckets, clamped).
// ---------------------------------------------------------------------------
__global__ __launch_bounds__(256) void deg_hist(
    const int* __restrict__ cnt, int* __restrict__ bhist, int n) {
    __shared__ int lh[64];
    if (threadIdx.x < 64) lh[threadIdx.x] = 0;
    __syncthreads();
    for (int i = blockIdx.x * 256 + threadIdx.x; i < n; i += gridDim.x * 256) {
        int c = cnt[i]; if (c > 63) c = 63;
        atomicAdd(&lh[c], 1);
    }
    __syncthreads();
    if (threadIdx.x < 64) atomicAdd(&bhist[threadIdx.x], lh[threadIdx.x]);
}

__global__ __launch_bounds__(256) void deg_scatter(
    const int* __restrict__ cnt, int* __restrict__ bcur,
    int* __restrict__ order, int n) {
    __shared__ int lh[64];
    __shared__ int lbase[64];
    if (threadIdx.x < 64) lh[threadIdx.x] = 0;
    __syncthreads();
    const int i = blockIdx.x * 256 + threadIdx.x;
    int c = 0, lpos = 0;
    if (i < n) {
        c = cnt[i]; if (c > 63) c = 63;
        lpos = atomicAdd(&lh[c], 1);
    }
    __syncthreads();
    if (threadIdx.x < 64 && lh[threadIdx.x] > 0)
        lbase[threadIdx.x] = atomicAdd(&bcur[threadIdx.x], lh[threadIdx.x]);
    __syncthreads();
    if (i < n) order[lbase[c] + lpos] = i;
}

// ---------------------------------------------------------------------------
// Fused single-pass per-dst softmax + aggregation, degree-ordered,
// 4x-unrolled inner loop (4 independent gather chains in flight).
// ---------------------------------------------------------------------------
template<int F, int D>
__global__ __launch_bounds__(256) void csr_attn_agg_dual(
    const int* __restrict__ order,
    const int* __restrict__ perm, const int* __restrict__ offsets,
    const int* __restrict__ counts,
    const float* __restrict__ asrcP, const float* __restrict__ adstP,
    const _Float16* __restrict__ hP, _Float16* __restrict__ outA,
    const float* __restrict__ asrcA, const float* __restrict__ adstA,
    const _Float16* __restrict__ hA, _Float16* __restrict__ outP,
    int N) {
    constexpr int LPN = F / 4;
    const int gid  = blockIdx.x * 256 + threadIdx.x;
    const int slot = gid / LPN;
    const int lane = gid % LPN;
    if (slot >= 2 * N) return;
    const int node_g = order[slot];
    const bool second = node_g >= N;
    const int node = second ? node_g - N : node_g;
    const float* __restrict__ asrc    = second ? asrcA : asrcP;
    const float* __restrict__ adst    = second ? adstA : adstP;
    const _Float16* __restrict__ hsrc = second ? hA : hP;
    _Float16* __restrict__ out        = second ? outP : outA;

    const int start = offsets[node_g];
    const int cnt   = counts[node_g];
    const int f0 = lane * 4;
    const int h  = f0 / D;
    const float ad = adst[(size_t)node * HEADS + h];

    float den = 0.f;
    float4 acc = make_float4(0.f, 0.f, 0.f, 0.f);
    int i = 0;
    for (; i + 4 <= cnt; i += 4) {
        const int s0 = perm[start + i + 0];
        const int s1 = perm[start + i + 1];
        const int s2 = perm[start + i + 2];
        const int s3 = perm[start + i + 3];
        const float a0 = asrc[(size_t)s0 * HEADS + h];
        const float a1 = asrc[(size_t)s1 * HEADS + h];
        const float a2 = asrc[(size_t)s2 * HEADS + h];
        const float a3 = asrc[(size_t)s3 * HEADS + h];
        f16x4 h0 = *(const f16x4*)(hsrc + (size_t)s0 * F + f0);
        f16x4 h1 = *(const f16x4*)(hsrc + (size_t)s1 * F + f0);
        f16x4 h2 = *(const f16x4*)(hsrc + (size_t)s2 * F + f0);
        f16x4 h3 = *(const f16x4*)(hsrc + (size_t)s3 * F + f0);
        const float e0 = __expf(leaky02(a0 + ad));
        const float e1 = __expf(leaky02(a1 + ad));
        const float e2 = __expf(leaky02(a2 + ad));
        const float e3 = __expf(leaky02(a3 + ad));
        den += (e0 + e1) + (e2 + e3);
        acc.x += e0 * (float)h0[0] + e1 * (float)h1[0] + e2 * (float)h2[0] + e3 * (float)h3[0];
        acc.y += e0 * (float)h0[1] + e1 * (float)h1[1] + e2 * (float)h2[1] + e3 * (float)h3[1];
        acc.z += e0 * (float)h0[2] + e1 * (float)h1[2] + e2 * (float)h2[2] + e3 * (float)h3[2];
        acc.w += e0 * (float)h0[3] + e1 * (float)h1[3] + e2 * (float)h2[3] + e3 * (float)h3[3];
    }
    for (; i < cnt; ++i) {
        const int s = perm[start + i];
        const float a = leaky02(asrc[(size_t)s * HEADS + h] + ad);
        const float ex = __expf(a);
        den += ex;
        f16x4 hv = *(const f16x4*)(hsrc + (size_t)s * F + f0);
        acc.x += ex * (float)hv[0]; acc.y += ex * (float)hv[1];
        acc.z += ex * (float)hv[2]; acc.w += ex * (float)hv[3];
    }
    const float inv = 1.f / (den + 1e-16f);
    f16x4 o;
    o[0] = (_Float16)fmaxf(acc.x * inv, 0.f);
    o[1] = (_Float16)fmaxf(acc.y * inv, 0.f);
    o[2] = (_Float16)fmaxf(acc.z * inv, 0.f);
    o[3] = (_Float16)fmaxf(acc.w * inv, 0.f);
    *(f16x4*)(out + (size_t)node * F + f0) = o;
}

// ---------------------------------------------------------------------------
// Final: out[l] = dot(zp[eli0[l]], za[eli1[l]]), 64 fp16 feats -> fp32.
// ---------------------------------------------------------------------------
__global__ __launch_bounds__(256) void edge_dot(
    const int* __restrict__ eli, const _Float16* __restrict__ zp,
    const _Float16* __restrict__ za, float* __restrict__ out, int L) {
    constexpr int LPE = 16;
    const int gid  = blockIdx.x * blockDim.x + threadIdx.x;
    const int e    = gid / LPE;
    const int lane = gid % LPE;
    if (e >= L) return;
    const int p = eli[e], a = eli[(size_t)L + e];
    f16x4 pv = *(const f16x4*)(zp + (size_t)p * 64 + lane * 4);
    f16x4 av = *(const f16x4*)(za + (size_t)a * 64 + lane * 4);
    float s = (float)pv[0] * (float)av[0] + (float)pv[1] * (float)av[1]
            + (float)pv[2] * (float)av[2] + (float)pv[3] * (float)av[3];
    #pragma unroll
    for (int off = 8; off > 0; off >>= 1) s += __shfl_xor(s, off);
    if (lane == 0) out[e] = s;
}

// ---------------------------------------------------------------------------
static inline int cdiv(long long a, long long b) { return (int)((a + b - 1) / b); }

extern "C" void kernel_launch(void* const* d_in, const int* in_sizes, int n_in,
                              void* d_out, int out_size, void* d_ws, size_t ws_size,
                              hipStream_t stream) {
    const float* x_p  = (const float*)d_in[0];
    const float* x_a  = (const float*)d_in[1];
    const int* ei_pa  = (const int*)d_in[2];
    const int* ei_ap  = (const int*)d_in[3];
    const int* eli    = (const int*)d_in[4];
    const float* p1W = (const float*)d_in[5];
    const float* p1b = (const float*)d_in[6];
    const float* a1W = (const float*)d_in[7];
    const float* a1b = (const float*)d_in[8];
    const float* s1pa = (const float*)d_in[9];
    const float* d1pa = (const float*)d_in[10];
    const float* s1ap = (const float*)d_in[11];
    const float* d1ap = (const float*)d_in[12];
    // 13..15: k1W, k1b, q1 — dead (single-metapath group == identity)
    const float* p2W = (const float*)d_in[16];
    const float* p2b = (const float*)d_in[17];
    const float* a2W = (const float*)d_in[18];
    const float* a2b = (const float*)d_in[19];
    const float* s2pa = (const float*)d_in[20];
    const float* d2pa = (const float*)d_in[21];
    const float* s2ap = (const float*)d_in[22];
    const float* d2ap = (const float*)d_in[23];
    // 24..26: k2W, k2b, q2 — dead

    const int NP = in_sizes[0] / 128;
    const int E  = in_sizes[2] / 2;
    const int L  = in_sizes[4] / 2;
    const int N  = NP;  // NP == NA

    // ---- workspace layout ----
    char* ws = (char*)d_ws;
    size_t off = 0;
    auto alloc = [&](size_t bytes) -> char* {
        char* p = ws + off;
        off += (bytes + 255) & ~(size_t)255;
        return p;
    };
    _Float16* h_p1   = (_Float16*)alloc((size_t)N * 128 * 2);
    _Float16* h_a1   = (_Float16*)alloc((size_t)N * 128 * 2);
    _Float16* out_p1 = (_Float16*)alloc((size_t)N * 128 * 2);
    _Float16* out_a1 = (_Float16*)alloc((size_t)N * 128 * 2);
    _Float16* h_p2   = (_Float16*)alloc((size_t)N * 64 * 2);
    _Float16* h_a2   = (_Float16*)alloc((size_t)N * 64 * 2);
    _Float16* out_p2 = (_Float16*)alloc((size_t)N * 64 * 2);
    _Float16* out_a2 = (_Float16*)alloc((size_t)N * 64 * 2);
    float* asrc_pa = (float*)alloc((size_t)N * HEADS * 4);
    float* adst_pa = (float*)alloc((size_t)N * HEADS * 4);
    float* asrc_ap = (float*)alloc((size_t)N * HEADS * 4);
    float* adst_ap = (float*)alloc((size_t)N * HEADS * 4);
    _Float16* Wf1p = (_Float16*)alloc(16384 * 2);
    _Float16* Wf1a = (_Float16*)alloc(16384 * 2);
    _Float16* Wf2p = (_Float16*)alloc(8192 * 2);
    _Float16* Wf2a = (_Float16*)alloc(8192 * 2);
    // cnt2 / cursor2 / bhist are contiguous: one memset covers them
    int* cnt2    = (int*)alloc((size_t)2 * N * 4);
    int* cursor2 = (int*)alloc((size_t)2 * N * 4);
    int* bhist   = (int*)alloc(256);            // 64 ints
    int* off2    = (int*)alloc((size_t)2 * N * 4);
    int* perm2   = (int*)alloc((size_t)2 * E * 4);
    int* order2  = (int*)alloc((size_t)2 * N * 4);
    int* bsum    = (int*)alloc(256 * 4);

    const int* src_pa = ei_pa;       // papers
    const int* dst_pa = ei_pa + E;   // authors
    const int* src_ap = ei_ap;       // authors
    const int* dst_ap = ei_ap + E;   // papers

    const int N2 = 2 * N;
    const int nbScan = cdiv(N2, 1024);

    // ================= prep + CSR build + degree sort =================
    prep_w4<<<cdiv(49152, 256), 256, 0, stream>>>(p1W, Wf1p, a1W, Wf1a, p2W, Wf2p, a2W, Wf2a);
    hipMemsetAsync(cnt2, 0, ((size_t)4 * N + 64) * 4, stream);  // cnt2+cursor2+bhist
    hist_dual<<<cdiv((long long)2 * E, 256), 256, 0, stream>>>(dst_pa, dst_ap, cnt2, N, E);
    scan_blk<<<nbScan, 256, 0, stream>>>(cnt2, off2, bsum, N2);
    scan_sums<<<1, 256, 0, stream>>>(bsum, nbScan);
    scan_add<<<nbScan, 256, 0, stream>>>(off2, bsum, N2);
    scatter_dual<<<cdiv((long long)2 * E, 256), 256, 0, stream>>>(
        src_pa, dst_pa, src_ap, dst_ap, off2, cursor2, perm2, N, E);
    deg_hist<<<256, 256, 0, stream>>>(cnt2, bhist, N2);
    scan_sums<<<1, 256, 0, stream>>>(bhist, 64);
    deg_scatter<<<cdiv(N2, 256), 256, 0, stream>>>(cnt2, bhist, order2, N2);

    const int nbHalf = cdiv(N, 64);

    // ================= Layer 1 =================
    gemm_mfma_dual<128, false><<<2 * nbHalf, 256, 0, stream>>>(
        x_p, Wf1p, p1b, h_p1, s1pa, d1ap, asrc_pa, adst_ap,
        x_a, Wf1a, a1b, h_a1, s1ap, d1pa, asrc_ap, adst_pa, N, nbHalf);
    csr_attn_agg_dual<128, 32><<<cdiv((long long)N2 * 32, 256), 256, 0, stream>>>(
        order2, perm2, off2, cnt2,
        asrc_pa, adst_pa, h_p1, out_a1,
        asrc_ap, adst_ap, h_a1, out_p1, N);

    // ================= Layer 2 =================
    gemm_mfma_dual<64, true><<<2 * nbHalf, 256, 0, stream>>>(
        out_p1, Wf2p, p2b, h_p2, s2pa, d2ap, asrc_pa, adst_ap,
        out_a1, Wf2a, a2b, h_a2, s2ap, d2pa, asrc_ap, adst_pa, N, nbHalf);
    csr_attn_agg_dual<64, 16><<<cdiv((long long)N2 * 16, 256), 256, 0, stream>>>(
        order2, perm2, off2, cnt2,
        asrc_pa, adst_pa, h_p2, out_a2,
        asrc_ap, adst_ap, h_a2, out_p2, N);

    // ================= Final dot =================
    edge_dot<<<cdiv((long long)L * 16, 256), 256, 0, stream>>>(
        eli, out_p2, out_a2, (float*)d_out, L);
}